// Round 4
// baseline (156.776 us; speedup 1.0000x reference)
//
#include <hip/hip_runtime.h>

// Problem dims (fixed by reference)
#define Bq 32
#define Sq 64
#define Iq 256
#define Hq 256
#define Oq 128
#define Fq 512          // Iq + Hq
#define WPB 8           // workgroups per batch
#define NT 512          // threads per workgroup
#define PRE_S 62        // x steps preloaded in LDS: 62KB + 1KB hbuf + flag <= 64KB

// R8: register-residency fix. Evidence from R7: VGPR_Count=104 (< the 128
// floats of per-thread state) AND FETCH_SIZE=9.8MB vs 3.4MB of true inputs
// -> the compiler RELOADS the loop-invariant fw/fl/fg from memory every
// step (rematerialization heuristic), 192KB/CU working set misses L1 and
// partially misses XCD L2 -> ~6.4MB/dispatch of HBM re-fetch sitting in the
// shadow phase's critical path with only 2 waves/SIMD to hide it. That also
// explains why R6's transport surgery was neutral (shadow paces the step).
// Fix: opaque-register pinning via empty asm ("+v") after the prologue
// loads -- reload becomes illegal, state must stay in VGPRs/AGPRs (AGPR
// moves ~1cy << L2/HBM reloads ~300+cy).
// Micro: s_setprio(1) around wave0's transport (poll->hbuf->flag) so the
// critical wave wins issue arbitration vs its spinning SIMD-mate.
// Arithmetic is bit-frozen R7 (incl. fast tanh); transport protocol frozen.
__global__ __launch_bounds__(NT, 1) void stpn_main(
    const float* __restrict__ x,     // (B,S,I)
    const float* __restrict__ w,     // (H,F)
    const float* __restrict__ wl,    // (H,F)
    const float* __restrict__ wgm,   // (H,F)
    const float* __restrict__ bias,  // (H)
    const float* __restrict__ ow,    // (O,H)
    const float* __restrict__ ob,    // (O)
    float* __restrict__ out,         // [tag(B*O) | h_fin(B*H) | f_fin(B*H*F)]
    unsigned long long* __restrict__ hb) // [2][B][H] (tag<<32|bits) slots
{
    const int blk   = blockIdx.x;
    const int b     = blk & 31;       // 8 wgs of a batch land round-robin
    const int chunk = blk >> 5;       // 0..7
    const int h0    = chunk * 32;
    const int tid   = threadIdx.x;
    const int lr    = tid & 15;       // lane within row
    const int r     = tid >> 4;       // row 0..31
    const int row   = h0 + r;
    const int ln    = tid & 63;       // lane within wave
    const int wv    = tid >> 6;       // wave id within wg

    __shared__ float xall[PRE_S * Iq];   // 62 KB
    __shared__ float hbuf[Hq];           // 1 KB: h_{t-1} broadcast buffer
    __shared__ unsigned hflag;           // step tag of hbuf contents

    // Static params + fast-weight state in registers for all 64 steps.
    float fw[32], fl[32], fg[32], ff[32];
    const size_t rowoff = (size_t)row * Fq;
#pragma unroll
    for (int j = 0; j < 8; ++j) {
        const int c = 4 * lr + 64 * j;
        *(float4*)&fw[4*j] = *(const float4*)(w   + rowoff + c);
        *(float4*)&fl[4*j] = *(const float4*)(wl  + rowoff + c);
        *(float4*)&fg[4*j] = *(const float4*)(wgm + rowoff + c);
    }
    // PIN: make every static-param value opaque so the compiler cannot
    // rematerialize it by re-loading from memory inside the t-loop.
#pragma unroll
    for (int j = 0; j < 32; ++j) {
        asm volatile("" : "+v"(fw[j]));
        asm volatile("" : "+v"(fl[j]));
        asm volatile("" : "+v"(fg[j]));
    }
#pragma unroll
    for (int j = 0; j < 32; ++j) ff[j] = 0.f;

    // Prologue x preload: 62*256/4 = 3968 float4 = 512*7 + 384.
    {
        const float4* xs = (const float4*)(x + (size_t)b * Sq * Iq);
        float4* xd = (float4*)xall;
#pragma unroll
        for (int k = 0; k < 7; ++k)
            xd[tid + NT * k] = xs[tid + NT * k];
        if (tid < 384) xd[tid + 3584] = xs[tid + 3584];
    }
    if (tid < Hq) hbuf[tid] = 0.f;    // t=0 reads h = 0
    if (tid == 0) hflag = 0u;
    const float brow = bias[row];
    const float* xb = x + (size_t)b * Sq * Iq;
    __syncthreads();                  // covers preload + hbuf/hflag init

    for (int t = 0; t < Sq; ++t) {
        // ---- x-part of fused pre+nsq (js 0..3): no transport dependency ----
        float pre = 0.f, nsq = 0.f;
        if (t < PRE_S) {
            const float* xpart = xall + t * Iq;
#pragma unroll
            for (int j = 0; j < 4; ++j) {
                const float4 tv = *(const float4*)&xpart[4 * lr + 64 * j];
                float tw;
                tw = fw[4*j+0] + ff[4*j+0]; pre = fmaf(tv.x, tw, pre); nsq = fmaf(tw, tw, nsq);
                tw = fw[4*j+1] + ff[4*j+1]; pre = fmaf(tv.y, tw, pre); nsq = fmaf(tw, tw, nsq);
                tw = fw[4*j+2] + ff[4*j+2]; pre = fmaf(tv.z, tw, pre); nsq = fmaf(tw, tw, nsq);
                tw = fw[4*j+3] + ff[4*j+3]; pre = fmaf(tv.w, tw, pre); nsq = fmaf(tw, tw, nsq);
            }
        } else {
            const float* xpart = xb + (size_t)t * Iq;
#pragma unroll
            for (int j = 0; j < 4; ++j) {
                const float4 tv = *(const float4*)&xpart[4 * lr + 64 * j];
                float tw;
                tw = fw[4*j+0] + ff[4*j+0]; pre = fmaf(tv.x, tw, pre); nsq = fmaf(tw, tw, nsq);
                tw = fw[4*j+1] + ff[4*j+1]; pre = fmaf(tv.y, tw, pre); nsq = fmaf(tw, tw, nsq);
                tw = fw[4*j+2] + ff[4*j+2]; pre = fmaf(tv.z, tw, pre); nsq = fmaf(tw, tw, nsq);
                tw = fw[4*j+3] + ff[4*j+3]; pre = fmaf(tv.w, tw, pre); nsq = fmaf(tw, tw, nsq);
            }
        }

        // ---- transport: wave0 fetches h_{t-1}, siblings wait on LDS flag ----
        if (t > 0) {
            const unsigned tt = (unsigned)t;
            if (wv == 0) {
                __builtin_amdgcn_s_setprio(1);   // critical wave: win issue arb
                unsigned long long* s0 =
                    hb + (size_t)((t - 1) & 1) * Bq * Hq + (size_t)b * Hq + ln;
                unsigned long long v0, v1, v2, v3;
                do {
                    v0 = __hip_atomic_load(s0,       __ATOMIC_RELAXED, __HIP_MEMORY_SCOPE_AGENT);
                    v1 = __hip_atomic_load(s0 + 64,  __ATOMIC_RELAXED, __HIP_MEMORY_SCOPE_AGENT);
                    v2 = __hip_atomic_load(s0 + 128, __ATOMIC_RELAXED, __HIP_MEMORY_SCOPE_AGENT);
                    v3 = __hip_atomic_load(s0 + 192, __ATOMIC_RELAXED, __HIP_MEMORY_SCOPE_AGENT);
                } while (!((unsigned)(v0 >> 32) == tt && (unsigned)(v1 >> 32) == tt &&
                           (unsigned)(v2 >> 32) == tt && (unsigned)(v3 >> 32) == tt));
                hbuf[ln      ] = __uint_as_float((unsigned)(v0 & 0xffffffffu));
                hbuf[ln + 64 ] = __uint_as_float((unsigned)(v1 & 0xffffffffu));
                hbuf[ln + 128] = __uint_as_float((unsigned)(v2 & 0xffffffffu));
                hbuf[ln + 192] = __uint_as_float((unsigned)(v3 & 0xffffffffu));
                if (ln == 0)
                    __hip_atomic_store(&hflag, tt, __ATOMIC_RELEASE,
                                       __HIP_MEMORY_SCOPE_WORKGROUP);
                __builtin_amdgcn_s_setprio(0);
            } else {
                while (__hip_atomic_load(&hflag, __ATOMIC_ACQUIRE,
                                         __HIP_MEMORY_SCOPE_WORKGROUP) != tt) {}
            }
        }

        // ---- h-part (js 4..7); keep operands in regs for the shadow ----
        float4 hr[4];
#pragma unroll
        for (int jj = 0; jj < 4; ++jj)
            hr[jj] = *(const float4*)&hbuf[4 * lr + 64 * jj];
#pragma unroll
        for (int j = 4; j < 8; ++j) {
            const int jj = j - 4;
            float tw;
            tw = fw[4*j+0] + ff[4*j+0]; pre = fmaf(hr[jj].x, tw, pre); nsq = fmaf(tw, tw, nsq);
            tw = fw[4*j+1] + ff[4*j+1]; pre = fmaf(hr[jj].y, tw, pre); nsq = fmaf(tw, tw, nsq);
            tw = fw[4*j+2] + ff[4*j+2]; pre = fmaf(hr[jj].z, tw, pre); nsq = fmaf(tw, tw, nsq);
            tw = fw[4*j+3] + ff[4*j+3]; pre = fmaf(hr[jj].w, tw, pre); nsq = fmaf(tw, tw, nsq);
        }
#pragma unroll
        for (int m = 1; m < 16; m <<= 1) {
            pre += __shfl_xor(pre, m, 16);
            nsq += __shfl_xor(nsq, m, 16);
        }
        const float inv = __fdividef(1.0f, sqrtf(nsq) + 1e-16f);
        // tanh(z) = 1 - 2/(exp(2z)+1); saturates cleanly to +-1.
        const float z   = fmaf(pre, inv, brow);
        const float e2  = __expf(2.0f * z);
        const float hn  = 1.0f - __fdividef(2.0f, e2 + 1.0f);

        if (lr == 0) {
            const unsigned long long pk =
                ((unsigned long long)(unsigned)(t + 1) << 32) |
                (unsigned long long)__float_as_uint(hn);
            __hip_atomic_store(
                hb + (size_t)(t & 1) * Bq * Hq + (size_t)b * Hq + row, pk,
                __ATOMIC_RELAXED, __HIP_MEMORY_SCOPE_AGENT);
        }

        // ---- shadow: f update (x re-read; h from hr regs) ----
        if (t < PRE_S) {
            const float* xpart = xall + t * Iq;
#pragma unroll
            for (int j = 0; j < 4; ++j) {
                const float4 tv = *(const float4*)&xpart[4 * lr + 64 * j];
                ff[4*j+0] = fmaf(fl[4*j+0], ff[4*j+0] * inv, fg[4*j+0] * (hn * tv.x));
                ff[4*j+1] = fmaf(fl[4*j+1], ff[4*j+1] * inv, fg[4*j+1] * (hn * tv.y));
                ff[4*j+2] = fmaf(fl[4*j+2], ff[4*j+2] * inv, fg[4*j+2] * (hn * tv.z));
                ff[4*j+3] = fmaf(fl[4*j+3], ff[4*j+3] * inv, fg[4*j+3] * (hn * tv.w));
            }
        } else {
            const float* xpart = xb + (size_t)t * Iq;
#pragma unroll
            for (int j = 0; j < 4; ++j) {
                const float4 tv = *(const float4*)&xpart[4 * lr + 64 * j];
                ff[4*j+0] = fmaf(fl[4*j+0], ff[4*j+0] * inv, fg[4*j+0] * (hn * tv.x));
                ff[4*j+1] = fmaf(fl[4*j+1], ff[4*j+1] * inv, fg[4*j+1] * (hn * tv.y));
                ff[4*j+2] = fmaf(fl[4*j+2], ff[4*j+2] * inv, fg[4*j+2] * (hn * tv.z));
                ff[4*j+3] = fmaf(fl[4*j+3], ff[4*j+3] * inv, fg[4*j+3] * (hn * tv.w));
            }
        }
#pragma unroll
        for (int j = 4; j < 8; ++j) {
            const int jj = j - 4;
            ff[4*j+0] = fmaf(fl[4*j+0], ff[4*j+0] * inv, fg[4*j+0] * (hn * hr[jj].x));
            ff[4*j+1] = fmaf(fl[4*j+1], ff[4*j+1] * inv, fg[4*j+1] * (hn * hr[jj].y));
            ff[4*j+2] = fmaf(fl[4*j+2], ff[4*j+2] * inv, fg[4*j+2] * (hn * hr[jj].z));
            ff[4*j+3] = fmaf(fl[4*j+3], ff[4*j+3] * inv, fg[4*j+3] * (hn * hr[jj].w));
        }
    }

    // ---- f_fin: 16 lanes x float4 per row chunk ----
    float* fo = out + Bq * Oq + Bq * Hq + (size_t)b * Hq * Fq + rowoff;
#pragma unroll
    for (int j = 0; j < 8; ++j) {
        const int c = 4 * lr + 64 * j;
        *(float4*)(fo + c) = *(const float4*)&ff[4*j];
    }

    // ---- epilogue (chunk-0 wg per batch): h_fin + tag_space ----
    if (chunk == 0) {
        __syncthreads();   // all waves past their last hbuf read before reuse
        if (tid < Hq) {
            unsigned long long* slot =
                hb + (size_t)1 * Bq * Hq + (size_t)b * Hq + tid;  // t=63 -> parity 1
            unsigned long long v;
            do {
                v = __hip_atomic_load(slot, __ATOMIC_RELAXED,
                                      __HIP_MEMORY_SCOPE_AGENT);
            } while ((unsigned)(v >> 32) != (unsigned)Sq);
            const float hv = __uint_as_float((unsigned)(v & 0xffffffffu));
            hbuf[tid] = hv;
            out[Bq * Oq + (size_t)b * Hq + tid] = hv;     // h_fin
        }
        __syncthreads();
        // 512 threads = 128 outputs x 4 lanes; lane l sums cols 16k+4l..+3.
        const int o = tid >> 2;
        const int l = tid & 3;
        const float* wr = ow + (size_t)o * Hq;
        float acc = 0.f;
#pragma unroll
        for (int k = 0; k < 16; ++k) {
            const int cc = 16 * k + 4 * l;
            const float4 w4 = *(const float4*)(wr + cc);
            const float4 h4 = *(const float4*)&hbuf[cc];
            acc += w4.x * h4.x + w4.y * h4.y + w4.z * h4.z + w4.w * h4.w;
        }
        acc += __shfl_xor(acc, 1, 4);
        acc += __shfl_xor(acc, 2, 4);
        if (l == 0) out[(size_t)b * Oq + o] = acc + ob[o];
    }
}

extern "C" void kernel_launch(void* const* d_in, const int* in_sizes, int n_in,
                              void* d_out, int out_size, void* d_ws, size_t ws_size,
                              hipStream_t stream)
{
    const float* x    = (const float*)d_in[0];
    const float* w    = (const float*)d_in[1];
    const float* wl   = (const float*)d_in[2];
    const float* wgm  = (const float*)d_in[3];
    const float* bias = (const float*)d_in[4];
    const float* ow   = (const float*)d_in[5];
    const float* ob   = (const float*)d_in[6];
    float* out = (float*)d_out;

    // Zero the (tag,val) h-exchange slots: 2 * B * H * 8 bytes = 128 KB.
    hipMemsetAsync(d_ws, 0, 2 * Bq * Hq * sizeof(unsigned long long), stream);

    stpn_main<<<Bq * WPB, NT, 0, stream>>>(x, w, wl, wgm, bias, ow, ob, out,
                                           (unsigned long long*)d_ws);
}